// Round 11
// baseline (195.234 us; speedup 1.0000x reference)
//
#include <hip/hip_runtime.h>
#include <math.h>

// Problem constants
#define B_ 2
#define S_ 8193
#define L_ 8192
#define E_ 512
#define H_ 8
#define D_ 64
#define QKV_COLS 1536   // 3*E
#define SCALE 0.125f
#define M_ROWS 16386    // B*S
#define M_PAD 16512     // round up to 128 (out-proj GEMM)
#define M_PAD2 16640    // round up to 256 (qkv GEMM)

typedef unsigned short u16;
typedef __attribute__((ext_vector_type(8))) short bf16x8;
typedef __attribute__((ext_vector_type(8))) unsigned short u16x8;
typedef __attribute__((ext_vector_type(4))) float f32x4;

__device__ __forceinline__ u16 f2bf(float f) {
    unsigned u = __float_as_uint(f);
    unsigned r = (u + 0x7fffu + ((u >> 16) & 1u)) >> 16;   // RNE
    return (u16)r;
}
__device__ __forceinline__ float bf2f(u16 h) {
    return __uint_as_float((unsigned)h << 16);
}

__device__ __forceinline__ void gload_lds16(const void* g, void* l) {
    __builtin_amdgcn_global_load_lds(
        (const __attribute__((address_space(1))) void*)g,
        (__attribute__((address_space(3))) void*)l, 16, 0, 0);
}

#define WAITV8() asm volatile("s_waitcnt vmcnt(8)" ::: "memory")
#define WAITV4() asm volatile("s_waitcnt vmcnt(4)" ::: "memory")
#define WAITV0() asm volatile("s_waitcnt vmcnt(0)" ::: "memory")
#define BAR()    __builtin_amdgcn_s_barrier()

// ---------------------------------------------------------------------------
// float -> bf16 conversion, 512 cols, zero-pads rows >= rows.
// ---------------------------------------------------------------------------
__global__ __launch_bounds__(256) void convert_bf16_512(
    const float* __restrict__ src, u16* __restrict__ dst, int rows, long total4)
{
    const long i = (long)blockIdx.x * 256 + threadIdx.x;
    if (i >= total4) return;
    const long f = i * 4;
    const long row = f >> 9;
    ushort4 o;
    if (row < rows) {
        const float4 v = *(const float4*)(src + f);
        o.x = f2bf(v.x); o.y = f2bf(v.y); o.z = f2bf(v.z); o.w = f2bf(v.w);
    } else {
        o = make_ushort4(0, 0, 0, 0);
    }
    *(ushort4*)(dst + f) = o;
}

// ---------------------------------------------------------------------------
// RoPE cos/sin table: tab[bl*32 + p2] = {cos, sin}
// ---------------------------------------------------------------------------
__global__ __launch_bounds__(256) void rope_table_kernel(
    const int* __restrict__ coords, float2* __restrict__ tab)
{
    const int i = blockIdx.x * 256 + threadIdx.x;   // bl*32 + p2
    const int p2 = i & 31;
    const int bl = i >> 5;
    const float coord = (float)coords[(size_t)bl * 2 + (p2 >> 4)] * 1e-5f;
    const float inv = exp2f(-0.83048202372184f * (float)(p2 & 15));
    float sn, cs;
    __sincosf(coord * inv, &sn, &cs);
    tab[i] = make_float2(cs, sn);
}

// ---------------------------------------------------------------------------
// QKV GEMM, 256x256 tile, 8 waves (2M x 4N), BK=64, depth-2 counted-vmcnt
// ring, chunk-XOR LDS swizzle (pre-swizzled global source), fused RoPE,
// LDS-staged coalesced bf16 C-write.
// A: M_PAD2 x K bf16 (zero-padded), W: N x K bf16, C: M x N bf16.
// K == 512 (8 K-tiles of 64). Per-wave output 128x64 (8x4 16x16 frags).
// LDS slot (row, phys) holds global chunk phys ^ (row&7); read with same XOR.
// ---------------------------------------------------------------------------
__global__ __launch_bounds__(512, 2) void gemm_qkv_256(
    const u16* __restrict__ A, const u16* __restrict__ W,
    const float* __restrict__ bias, u16* __restrict__ C,
    const float2* __restrict__ tab, int M, int N, int K)
{
    // 128 KB: buf b at smem + b*32768 (A 16384 u16, then B 16384 u16).
    // Epilogue reuses all 128 KB as the 256x256 bf16 staging tile.
    __shared__ __align__(16) u16 smem[65536];

    // XCD-aware bijective swizzle (m204)
    const int nwg = gridDim.x * gridDim.y;
    const int orig = blockIdx.y * gridDim.x + blockIdx.x;
    const int qq = nwg >> 3, rr = nwg & 7;
    const int xcd = orig & 7, off = orig >> 3;
    const int wgid = (xcd < rr ? xcd * (qq + 1) : rr * (qq + 1) + (xcd - rr) * qq) + off;
    const int m0 = (wgid / gridDim.x) * 256;
    const int n0 = (wgid % gridDim.x) * 256;

    const int tid  = threadIdx.x;
    const int wid  = tid >> 6;
    const int lane = tid & 63;
    const int wm = (wid >> 2) * 128;   // 2 M-waves
    const int wn = (wid & 3) * 64;     // 4 N-waves
    const int fr = lane & 15;
    const int fq = lane >> 4;          // 0..3

    f32x4 acc[8][4] = {};

    // stage one K-tile pair: 4 A-slots + 4 B-slots per thread (8 gloads).
    // slot = j*512 + tid; row = slot>>3; phys chunk = slot&7;
    // global chunk = phys ^ (row&7)  (inverse of read-side XOR).
    #define STAGE2(buf, k0)                                                     \
        do {                                                                    \
            u16* sa_ = smem + (buf) * 32768;                                    \
            u16* sb_ = sa_ + 16384;                                             \
            _Pragma("unroll")                                                   \
            for (int j2 = 0; j2 < 4; ++j2) {                                    \
                const int slot = j2 * 512 + tid;                                \
                const int row_ = slot >> 3;                                     \
                const int gch = (slot & 7) ^ (row_ & 7);                        \
                gload_lds16(A + (size_t)(m0 + row_) * K + (k0) + gch * 8,       \
                            sa_ + slot * 8);                                    \
                gload_lds16(W + (size_t)(n0 + row_) * K + (k0) + gch * 8,       \
                            sb_ + slot * 8);                                    \
            }                                                                   \
        } while (0)

    // one K-tile of MFMA: 2 k-chunks x (4 B-frags, 8 A-frags, 32 MFMA)
    #define COMPUTE2(buf)                                                       \
        do {                                                                    \
            const u16* sa_ = smem + (buf) * 32768;                              \
            const u16* sb_ = sa_ + 16384;                                       \
            _Pragma("unroll")                                                   \
            for (int kk = 0; kk < 2; ++kk) {                                    \
                const int cch = kk * 4 + fq;                                    \
                bf16x8 b[4];                                                    \
                _Pragma("unroll")                                               \
                for (int ni = 0; ni < 4; ++ni) {                                \
                    const int r_ = wn + ni * 16 + fr;                           \
                    b[ni] = *(const bf16x8*)(sb_ + r_ * 64 + ((cch ^ (r_ & 7)) * 8)); \
                }                                                               \
                _Pragma("unroll")                                               \
                for (int mi = 0; mi < 8; ++mi) {                                \
                    const int r_ = wm + mi * 16 + fr;                           \
                    const bf16x8 av = *(const bf16x8*)(sa_ + r_ * 64 + ((cch ^ (r_ & 7)) * 8)); \
                    _Pragma("unroll")                                           \
                    for (int ni = 0; ni < 4; ++ni)                              \
                        acc[mi][ni] = __builtin_amdgcn_mfma_f32_16x16x32_bf16(  \
                            av, b[ni], acc[mi][ni], 0, 0, 0);                   \
                }                                                               \
            }                                                                   \
        } while (0)

    const int nt = K / 64;   // 8

    STAGE2(0, 0);
    STAGE2(1, 64);

    int t = 0;
    for (; t < nt - 2; ++t) {
        WAITV8(); BAR();          // tile t landed for all waves
        COMPUTE2(t & 1);
        BAR();                    // all waves done reading buf before reuse
        STAGE2(t & 1, (t + 2) * 64);
    }
    WAITV8(); BAR(); COMPUTE2(t & 1); BAR(); ++t;
    WAITV0(); BAR(); COMPUTE2(t & 1);

    #undef STAGE2
    #undef COMPUTE2

    __syncthreads();   // release LDS ring; reuse as C staging

    // epilogue: bias + RoPE in regs -> LDS tile -> coalesced 16B stores
    u16* st = smem;                           // 256 x 256 bf16
    const bool rope_blk = (n0 < 2 * E_);      // q or k column tiles
    #pragma unroll
    for (int mi = 0; mi < 8; ++mi) {
        #pragma unroll
        for (int j = 0; j < 4; ++j) {
            const int row = wm + mi * 16 + fq * 4 + j;
            const int gm = m0 + row;
            int b = 0, s = gm;
            if (gm >= S_) { b = 1; s = gm - S_; }
            const bool rot = rope_blk && (gm < M) && (s > 0);
            const float2* trow = tab + ((size_t)(b * L_ + (s - 1)) << 5);
            #pragma unroll
            for (int ni = 0; ni < 4; ++ni) {
                const int col = wn + ni * 16 + fr;
                const int gn = n0 + col;
                float v = acc[mi][ni][j] + bias[gn];
                const float partner = __shfl_xor(v, 1, 64);  // gn^1 lives in lane^1
                if (rot) {
                    const float2 tt = trow[(gn & 63) >> 1];
                    v = (gn & 1) ? (v * tt.x + partner * tt.y)
                                 : (v * tt.x - partner * tt.y);
                }
                st[row * 256 + col] = f2bf(v);
            }
        }
    }
    __syncthreads();
    #pragma unroll
    for (int i = 0; i < 16; ++i) {
        const int slot = i * 512 + tid;
        const int row = slot >> 5;
        const int ch = slot & 31;
        const int gm = m0 + row;
        if (gm < M)
            *(u16x8*)(C + (size_t)gm * N + n0 + ch * 8) =
                *(const u16x8*)(st + row * 256 + ch * 8);
    }
}

// ---------------------------------------------------------------------------
// Out-proj GEMM (fp32 out), 128x128 tile, depth-3 counted-vmcnt pipeline,
// LDS-staged coalesced C-write. (Round-10 kernel, MODE 0 only.)
// ---------------------------------------------------------------------------
__global__ __launch_bounds__(256) void gemm_out_128(
    const u16* __restrict__ A, const u16* __restrict__ W,
    const float* __restrict__ bias, float* __restrict__ C,
    int M, int N, int K)
{
    __shared__ __align__(16) u16 smem[32768];

    const int nwg = gridDim.x * gridDim.y;
    const int orig = blockIdx.y * gridDim.x + blockIdx.x;
    const int qq = nwg >> 3, rr = nwg & 7;
    const int xcd = orig & 7, off = orig >> 3;
    const int wgid = (xcd < rr ? xcd * (qq + 1) : rr * (qq + 1) + (xcd - rr) * qq) + off;
    const int m0 = (wgid / gridDim.x) * 128;
    const int n0 = (wgid % gridDim.x) * 128;

    const int tid  = threadIdx.x;
    const int wid  = tid >> 6;
    const int lane = tid & 63;
    const int wm = (wid >> 1) * 64;
    const int wn = (wid & 1) * 64;

    const int srow = lane >> 2;
    const int scol = ((lane & 3) ^ ((lane >> 3) & 3)) * 8;
    const int fr = lane & 15;
    const int fq = lane >> 4;
    const int sfq = (fq ^ ((fr >> 1) & 3)) * 8;

    const int c0 = wid * 2, c1 = wid * 2 + 1;
    const u16* ga0 = A + (size_t)(m0 + c0 * 16 + srow) * K + scol;
    const u16* ga1 = A + (size_t)(m0 + c1 * 16 + srow) * K + scol;
    const u16* gb0 = W + (size_t)(n0 + c0 * 16 + srow) * K + scol;
    const u16* gb1 = W + (size_t)(n0 + c1 * 16 + srow) * K + scol;
    const int la0 = c0 * 16 * 32, la1 = c1 * 16 * 32;

    f32x4 acc[4][4] = {};

    #define STAGE(bi, k0)                                       \
        do {                                                    \
            u16* as_ = smem + (bi) * 4096;                      \
            u16* bs_ = smem + 16384 + (bi) * 4096;              \
            gload_lds16(ga0 + (k0), as_ + la0);                 \
            gload_lds16(ga1 + (k0), as_ + la1);                 \
            gload_lds16(gb0 + (k0), bs_ + la0);                 \
            gload_lds16(gb1 + (k0), bs_ + la1);                 \
        } while (0)

    #define COMPUTE(bi)                                                          \
        do {                                                                     \
            const u16* as_ = smem + (bi) * 4096;                                 \
            const u16* bs_ = smem + 16384 + (bi) * 4096;                         \
            bf16x8 a[4], b[4];                                                   \
            _Pragma("unroll")                                                    \
            for (int mi = 0; mi < 4; ++mi)                                       \
                a[mi] = *(const bf16x8*)(as_ + (wm + mi * 16 + fr) * 32 + sfq);  \
            _Pragma("unroll")                                                    \
            for (int ni = 0; ni < 4; ++ni)                                       \
                b[ni] = *(const bf16x8*)(bs_ + (wn + ni * 16 + fr) * 32 + sfq);  \
            _Pragma("unroll")                                                    \
            for (int mi = 0; mi < 4; ++mi)                                       \
                _Pragma("unroll")                                                \
                for (int ni = 0; ni < 4; ++ni)                                   \
                    acc[mi][ni] = __builtin_amdgcn_mfma_f32_16x16x32_bf16(       \
                        a[mi], b[ni], acc[mi][ni], 0, 0, 0);                     \
        } while (0)

    const int nt = K / 32;

    STAGE(0, 0);
    STAGE(1, 32);
    STAGE(2, 64);

    int t = 0;
    for (; t <= nt - 4; ++t) {
        WAITV8(); BAR();
        COMPUTE(t & 3);
        BAR();
        STAGE((t + 3) & 3, (t + 3) * 32);
    }
    WAITV8(); BAR(); COMPUTE(t & 3); ++t;
    WAITV4(); BAR(); COMPUTE(t & 3); ++t;
    WAITV0(); BAR(); COMPUTE(t & 3);

    #undef STAGE
    #undef COMPUTE

    __syncthreads();

    float* stf = (float*)smem;           // 128 x 128 f32 = 64 KB
    #pragma unroll
    for (int mi = 0; mi < 4; ++mi)
        #pragma unroll
        for (int j = 0; j < 4; ++j) {
            const int r = wm + mi * 16 + fq * 4 + j;
            #pragma unroll
            for (int ni = 0; ni < 4; ++ni) {
                const int c = wn + ni * 16 + fr;
                stf[r * 128 + c] = acc[mi][ni][j] + bias[n0 + c];
            }
        }
    __syncthreads();
    #pragma unroll
    for (int i = 0; i < 16; ++i) {
        const int ch = i * 256 + tid;
        const int row = ch >> 5;
        const int coff = (ch & 31) * 4;
        const int gm = m0 + row;
        if (gm < M)
            *(float4*)(C + (size_t)gm * N + n0 + coff) =
                *(const float4*)(stf + row * 128 + coff);
    }
}

// ---------------------------------------------------------------------------
// CLS attention stage 1 (bf16 qkv): flash over S chunks.
// ---------------------------------------------------------------------------
#define NCHUNK 64
#define CLS_ROWS 129   // ceil(8193/64)

__global__ __launch_bounds__(256) void cls_attn_stage1(
    const u16* __restrict__ qkvb, float* __restrict__ part)
{
    const int blk = blockIdx.x;
    const int bh = blk >> 6, ch = blk & 63;
    const int b = bh >> 3, h = bh & 7;
    const int wid = threadIdx.x >> 6, lane = threadIdx.x & 63;
    const size_t base = (size_t)b * S_ * QKV_COLS;

    const float q = bf2f(qkvb[base + h * D_ + lane]);

    const int lo = ch * CLS_ROWS;
    const int hi = (lo + CLS_ROWS < S_) ? lo + CLS_ROWS : S_;

    float m = -1e30f, lsum = 0.f, acc = 0.f;
    for (int j = lo + wid; j < hi; j += 4) {
        const size_t roff = base + (size_t)j * QKV_COLS;
        float t = q * bf2f(qkvb[roff + E_ + h * D_ + lane]);
        #pragma unroll
        for (int o = 32; o; o >>= 1) t += __shfl_xor(t, o, 64);
        t *= SCALE;
        const float mn = fmaxf(m, t);
        const float corr = __expf(m - mn);
        const float p = __expf(t - mn);
        lsum = lsum * corr + p;
        acc = acc * corr + p * bf2f(qkvb[roff + 2 * E_ + h * D_ + lane]);
        m = mn;
    }

    __shared__ float sm[4], sl[4], sacc[4][64];
    if (lane == 0) { sm[wid] = m; sl[wid] = lsum; }
    sacc[wid][lane] = acc;
    __syncthreads();
    if (wid == 0) {
        const float gm = fmaxf(fmaxf(sm[0], sm[1]), fmaxf(sm[2], sm[3]));
        float gl = 0.f, ga = 0.f;
        #pragma unroll
        for (int w = 0; w < 4; ++w) {
            const float c = __expf(sm[w] - gm);
            gl += sl[w] * c;
            ga += sacc[w][lane] * c;
        }
        float* pp = part + ((size_t)bh * NCHUNK + ch) * 66;
        if (lane == 0) { pp[0] = gm; pp[1] = gl; }
        pp[2 + lane] = ga;
    }
}

__global__ __launch_bounds__(64) void cls_attn_stage2(
    const float* __restrict__ part, u16* __restrict__ attnb)
{
    const int bh = blockIdx.x;
    const int lane = threadIdx.x;
    const int b = bh >> 3, h = bh & 7;
    float gm = -1e30f;
    for (int c = 0; c < NCHUNK; ++c)
        gm = fmaxf(gm, part[((size_t)bh * NCHUNK + c) * 66]);
    float gl = 0.f, ga = 0.f;
    for (int c = 0; c < NCHUNK; ++c) {
        const float* pp = part + ((size_t)bh * NCHUNK + c) * 66;
        const float w = __expf(pp[0] - gm);
        gl += pp[1] * w;
        ga += pp[2 + lane] * w;
    }
    attnb[(size_t)(b * S_) * E_ + h * D_ + lane] = f2bf(ga / gl);
}

// ---------------------------------------------------------------------------
// Patch attention: lane = query. Block = 128 threads (2 waves) = 128 queries.
// K then V staged sequentially in one XOR-swizzled LDS buffer.
// ---------------------------------------------------------------------------
#define PQT 128

__global__ __launch_bounds__(128) void patch_attn(
    const u16* __restrict__ qkvb, u16* __restrict__ attnb)
{
    const int blk = blockIdx.x;
    const int qt = blk & 63;
    const int h = (blk >> 6) & 7;
    const int b = blk >> 9;
    const int l0 = qt * PQT;
    const size_t base = (size_t)b * S_ * QKV_COLS;
    const int hoff = h * D_;

    __shared__ u16 kv[144 * 64];
    __shared__ float kc[64], vc[64];

    const int t = threadIdx.x;

    if (t < 64) kc[t] = bf2f(qkvb[base + E_ + hoff + t]);
    else        vc[t - 64] = bf2f(qkvb[base + 2 * E_ + hoff + (t - 64)]);

    #pragma unroll
    for (int i = 0; i < 9; ++i) {
        const int ci = i * 128 + t;
        const int r = ci >> 3, c = ci & 7;
        const int lg = l0 - 8 + r;
        u16x8 v = {};
        if (lg >= 0 && lg < L_)
            v = *(const u16x8*)(qkvb + base + (size_t)(1 + lg) * QKV_COLS + E_ + hoff + c * 8);
        *(u16x8*)(kv + r * 64 + ((c ^ (r & 7)) * 8)) = v;
    }
    __syncthreads();

    const int l = l0 + t;
    const size_t qrow = base + (size_t)(1 + l) * QKV_COLS + hoff;

    float s[10];
    #pragma unroll
    for (int w = 0; w < 10; ++w) s[w] = 0.f;

    #pragma unroll
    for (int c = 0; c < 8; ++c) {
        const u16x8 qv = *(const u16x8*)(qkvb + qrow + c * 8);
        float qf[8];
        #pragma unroll
        for (int i = 0; i < 8; ++i) qf[i] = bf2f(qv[i]);
        #pragma unroll
        for (int i = 0; i < 8; ++i) s[0] += qf[i] * kc[c * 8 + i];
        #pragma unroll
        for (int w = 0; w < 9; ++w) {
            const int kr = t + 2 * w;
            const u16x8 kk = *(const u16x8*)(kv + kr * 64 + ((c ^ (kr & 7)) * 8));
            #pragma unroll
            for (int i = 0; i < 8; ++i) s[1 + w] += qf[i] * bf2f(kk[i]);
        }
    }

    s[0] *= SCALE;
    #pragma unroll
    for (int w = 0; w < 9; ++w) {
        const int lp = l + 2 * w - 8;
        s[1 + w] = (lp >= 0 && lp < L_) ? s[1 + w] * SCALE : -1e30f;
    }
    float m = s[0];
    #pragma unroll
    for (int w = 1; w < 10; ++w) m = fmaxf(m, s[w]);
    float sum = 0.f;
    #pragma unroll
    for (int w = 0; w < 10; ++w) { s[w] = __expf(s[w] - m); sum += s[w]; }
    const float rsum = 1.0f / sum;

    __syncthreads();
    #pragma unroll
    for (int i = 0; i < 9; ++i) {
        const int ci = i * 128 + t;
        const int r = ci >> 3, c = ci & 7;
        const int lg = l0 - 8 + r;
        u16x8 v = {};
        if (lg >= 0 && lg < L_)
            v = *(const u16x8*)(qkvb + base + (size_t)(1 + lg) * QKV_COLS + 2 * E_ + hoff + c * 8);
        *(u16x8*)(kv + r * 64 + ((c ^ (r & 7)) * 8)) = v;
    }
    __syncthreads();

    const size_t orow = (size_t)(b * S_ + 1 + l) * E_ + hoff;
    #pragma unroll
    for (int c = 0; c < 8; ++c) {
        float acc[8];
        #pragma unroll
        for (int i = 0; i < 8; ++i) acc[i] = s[0] * vc[c * 8 + i];
        #pragma unroll
        for (int w = 0; w < 9; ++w) {
            const int vr = t + 2 * w;
            const u16x8 vv = *(const u16x8*)(kv + vr * 64 + ((c ^ (vr & 7)) * 8));
            #pragma unroll
            for (int i = 0; i < 8; ++i) acc[i] += s[1 + w] * bf2f(vv[i]);
        }
        u16x8 o;
        #pragma unroll
        for (int i = 0; i < 8; ++i) o[i] = f2bf(acc[i] * rsum);
        *(u16x8*)(attnb + orow + c * 8) = o;
    }
}

// ---------------------------------------------------------------------------
// Launch
// ---------------------------------------------------------------------------
extern "C" void kernel_launch(void* const* d_in, const int* in_sizes, int n_in,
                              void* d_out, int out_size, void* d_ws, size_t ws_size,
                              hipStream_t stream)
{
    const float* x      = (const float*)d_in[0];
    const int*   coords = (const int*)  d_in[1];
    const float* w_qkv  = (const float*)d_in[2];
    const float* b_qkv  = (const float*)d_in[3];
    const float* w_out  = (const float*)d_in[4];
    const float* b_out  = (const float*)d_in[5];
    float* out = (float*)d_out;

    // workspace layout
    u16*   qkvb  = (u16*)d_ws;                                // M_ROWS x 1536 bf16
    u16*   xb    = qkvb + (size_t)M_ROWS * QKV_COLS;          // M_PAD2 x 512 bf16
    u16*   attnb = xb;                                        // alias (x dead after qkv GEMM)
    u16*   wqb   = xb + (size_t)M_PAD2 * E_;                  // 1536 x 512
    u16*   wob   = wqb + (size_t)QKV_COLS * E_;               // 512 x 512
    float* part  = (float*)(wob + (size_t)E_ * E_);           // 16*64*66 floats
    float2* tab  = (float2*)(part + (size_t)16 * NCHUNK * 66);// B*L*32 float2 (4 MB)

    // 1. convert inputs to bf16 + rope table
    {
        const long t4x = (long)M_PAD2 * E_ / 4;
        convert_bf16_512<<<(t4x + 255) / 256, 256, 0, stream>>>(x, xb, M_ROWS, t4x);
        const long t4q = (long)QKV_COLS * E_ / 4;
        convert_bf16_512<<<(t4q + 255) / 256, 256, 0, stream>>>(w_qkv, wqb, QKV_COLS, t4q);
        const long t4o = (long)E_ * E_ / 4;
        convert_bf16_512<<<(t4o + 255) / 256, 256, 0, stream>>>(w_out, wob, E_, t4o);
        rope_table_kernel<<<(B_ * L_ * 32) / 256, 256, 0, stream>>>(coords, tab);
    }

    // 2. QKV projection + fused RoPE (table), bf16 out — 256x256 8-wave
    {
        dim3 grid(QKV_COLS / 256, M_PAD2 / 256);   // 6 x 65
        gemm_qkv_256<<<grid, 512, 0, stream>>>(
            xb, wqb, b_qkv, qkvb, tab, M_ROWS, QKV_COLS, E_);
    }

    // 3. CLS attention
    cls_attn_stage1<<<B_ * H_ * NCHUNK, 256, 0, stream>>>(qkvb, part);
    cls_attn_stage2<<<B_ * H_, 64, 0, stream>>>(part, attnb);

    // 4. Patch windowed attention
    patch_attn<<<B_ * H_ * (L_ / PQT), PQT, 0, stream>>>(qkvb, attnb);

    // 5. Output projection (fp32 out) — 128x128 pipeline
    {
        dim3 grid(E_ / 128, M_PAD / 128);
        gemm_out_128<<<grid, 256, 0, stream>>>(
            attnb, wob, b_out, out, M_ROWS, E_, E_);
    }
}

// Round 12
// 171.843 us; speedup vs baseline: 1.1361x; 1.1361x over previous
//
#include <hip/hip_runtime.h>
#include <math.h>

// Problem constants
#define B_ 2
#define S_ 8193
#define L_ 8192
#define E_ 512
#define H_ 8
#define D_ 64
#define QKV_COLS 1536   // 3*E
#define SCALE 0.125f
#define M_ROWS 16386    // B*S
#define M_PAD 16512     // round up to 128

typedef unsigned short u16;
typedef __attribute__((ext_vector_type(8))) short bf16x8;
typedef __attribute__((ext_vector_type(8))) unsigned short u16x8;
typedef __attribute__((ext_vector_type(4))) float f32x4;

__device__ __forceinline__ u16 f2bf(float f) {
    unsigned u = __float_as_uint(f);
    unsigned r = (u + 0x7fffu + ((u >> 16) & 1u)) >> 16;   // RNE
    return (u16)r;
}
__device__ __forceinline__ float bf2f(u16 h) {
    return __uint_as_float((unsigned)h << 16);
}

__device__ __forceinline__ void gload_lds16(const void* g, void* l) {
    __builtin_amdgcn_global_load_lds(
        (const __attribute__((address_space(1))) void*)g,
        (__attribute__((address_space(3))) void*)l, 16, 0, 0);
}

#define WAITV8() asm volatile("s_waitcnt vmcnt(8)" ::: "memory")
#define WAITV4() asm volatile("s_waitcnt vmcnt(4)" ::: "memory")
#define WAITV0() asm volatile("s_waitcnt vmcnt(0)" ::: "memory")
#define LGKM0()  asm volatile("s_waitcnt lgkmcnt(0)" ::: "memory")
#define BAR()    __builtin_amdgcn_s_barrier()

// ---------------------------------------------------------------------------
// float -> bf16 conversion, 512 cols, zero-pads rows >= rows (weights only).
// ---------------------------------------------------------------------------
__global__ __launch_bounds__(256) void convert_bf16_512(
    const float* __restrict__ src, u16* __restrict__ dst, int rows, long total4)
{
    const long i = (long)blockIdx.x * 256 + threadIdx.x;
    if (i >= total4) return;
    const long f = i * 4;
    const long row = f >> 9;
    ushort4 o;
    if (row < rows) {
        const float4 v = *(const float4*)(src + f);
        o.x = f2bf(v.x); o.y = f2bf(v.y); o.z = f2bf(v.z); o.w = f2bf(v.w);
    } else {
        o = make_ushort4(0, 0, 0, 0);
    }
    *(ushort4*)(dst + f) = o;
}

// ---------------------------------------------------------------------------
// RoPE cos/sin table: tab[bl*32 + p2] = {cos, sin}
// ---------------------------------------------------------------------------
__global__ __launch_bounds__(256) void rope_table_kernel(
    const int* __restrict__ coords, float2* __restrict__ tab)
{
    const int i = blockIdx.x * 256 + threadIdx.x;   // bl*32 + p2
    const int p2 = i & 31;
    const int bl = i >> 5;
    const float coord = (float)coords[(size_t)bl * 2 + (p2 >> 4)] * 1e-5f;
    const float inv = exp2f(-0.83048202372184f * (float)(p2 & 15));
    float sn, cs;
    __sincosf(coord * inv, &sn, &cs);
    tab[i] = make_float2(cs, sn);
}

// ---------------------------------------------------------------------------
// QKV GEMM with fused fp32->bf16 A-staging (reg-staged, T14) + fused RoPE.
// C = bf16( RoPE( X @ W^T + bias ) ).  X fp32 M x K, W bf16 N x K.
// 128x128 tile, BK=32, 4 waves. A: global f32 -> regs -> ds_write (swizzled);
// W: global_load_lds (pre-swizzled source). Depth-2 rings, ONE barrier/step.
// 32 KB LDS total; epilogue reuses it as the 128x128 bf16 staging tile.
// ---------------------------------------------------------------------------
__global__ __launch_bounds__(256) void gemm_qkv_fused(
    const float* __restrict__ X, const u16* __restrict__ W,
    const float* __restrict__ bias, u16* __restrict__ C,
    const float2* __restrict__ tab, int M, int N, int K)
{
    __shared__ __align__(16) u16 smem[16384];   // As0 As1 Bs0 Bs1 (8 KB each)

    // XCD-aware bijective swizzle (m204)
    const int nwg = gridDim.x * gridDim.y;
    const int orig = blockIdx.y * gridDim.x + blockIdx.x;
    const int qq = nwg >> 3, rr = nwg & 7;
    const int xcd = orig & 7, off = orig >> 3;
    const int wgid = (xcd < rr ? xcd * (qq + 1) : rr * (qq + 1) + (xcd - rr) * qq) + off;
    const int m0 = (wgid / gridDim.x) * 128;
    const int n0 = (wgid % gridDim.x) * 128;

    const int tid  = threadIdx.x;
    const int wid  = tid >> 6;
    const int lane = tid & 63;
    const int wm = (wid >> 1) * 64;
    const int wn = (wid & 1) * 64;
    const int fr = lane & 15;
    const int fq = lane >> 4;
    const int sfq = (fq ^ ((fr >> 1) & 3)) * 8;   // swizzled read chunk

    // A loader: thread covers rows r0+32i (i=0..3), col group c4 = tid&7
    const int r0 = tid >> 3;
    const int c4 = tid & 7;
    const int aoff = r0 * 32 + (((c4 >> 1) ^ ((r0 >> 1) & 3)) * 8) + (c4 & 1) * 4;

    // W loader (gload_lds, pre-swizzled source chunk)
    const int srow = lane >> 2;
    const int scol = ((lane & 3) ^ ((lane >> 3) & 3)) * 8;
    const int c0 = wid * 2, c1 = wid * 2 + 1;
    const u16* gb0 = W + (size_t)(n0 + c0 * 16 + srow) * K + scol;
    const u16* gb1 = W + (size_t)(n0 + c1 * 16 + srow) * K + scol;
    const int lb0 = c0 * 16 * 32, lb1 = c1 * 16 * 32;

    float4 ra[4];
    f32x4 acc[4][4] = {};

    #define ALOAD(k0)                                                           \
        do {                                                                    \
            _Pragma("unroll")                                                   \
            for (int i = 0; i < 4; ++i) {                                       \
                const int gm = m0 + r0 + 32 * i;                                \
                ra[i] = (gm < M)                                                \
                    ? *(const float4*)(X + (size_t)gm * K + (k0) + c4 * 4)      \
                    : make_float4(0.f, 0.f, 0.f, 0.f);                          \
            }                                                                   \
        } while (0)

    #define ADSW(buf)                                                           \
        do {                                                                    \
            u16* as_ = smem + (buf) * 4096;                                     \
            _Pragma("unroll")                                                   \
            for (int i = 0; i < 4; ++i) {                                       \
                ushort4 o;                                                      \
                o.x = f2bf(ra[i].x); o.y = f2bf(ra[i].y);                       \
                o.z = f2bf(ra[i].z); o.w = f2bf(ra[i].w);                       \
                *(ushort4*)(as_ + aoff + 1024 * i) = o;                         \
            }                                                                   \
        } while (0)

    #define WSTAGE(buf, k0)                                                     \
        do {                                                                    \
            u16* bs_ = smem + 8192 + (buf) * 4096;                              \
            gload_lds16(gb0 + (k0), bs_ + lb0);                                 \
            gload_lds16(gb1 + (k0), bs_ + lb1);                                 \
        } while (0)

    #define COMPUTE(buf)                                                         \
        do {                                                                     \
            const u16* as_ = smem + (buf) * 4096;                                \
            const u16* bs_ = smem + 8192 + (buf) * 4096;                         \
            bf16x8 a[4], b[4];                                                   \
            _Pragma("unroll")                                                    \
            for (int mi = 0; mi < 4; ++mi)                                       \
                a[mi] = *(const bf16x8*)(as_ + (wm + mi * 16 + fr) * 32 + sfq);  \
            _Pragma("unroll")                                                    \
            for (int ni = 0; ni < 4; ++ni)                                       \
                b[ni] = *(const bf16x8*)(bs_ + (wn + ni * 16 + fr) * 32 + sfq);  \
            _Pragma("unroll")                                                    \
            for (int mi = 0; mi < 4; ++mi)                                       \
                _Pragma("unroll")                                                \
                for (int ni = 0; ni < 4; ++ni)                                   \
                    acc[mi][ni] = __builtin_amdgcn_mfma_f32_16x16x32_bf16(       \
                        a[mi], b[ni], acc[mi][ni], 0, 0, 0);                     \
        } while (0)

    const int nt = K / 32;   // 16

    // prologue
    ALOAD(0); WSTAGE(0, 0);
    WAITV0();
    ADSW(0);
    ALOAD(32); WSTAGE(1, 32);
    LGKM0(); BAR();

    for (int t = 0; t < nt; ++t) {
        COMPUTE(t & 1);
        if (t + 1 < nt) {
            WAITV0();                 // A regs(t+1) + W lds(t+1) landed (covered by compute)
            ADSW((t + 1) & 1);        // target buf last read at t-1 (BAR'd)
            if (t + 2 < nt) ALOAD((t + 2) * 32);
            LGKM0(); BAR();           // ds_writes visible; all waves done COMPUTE(t)
            if (t + 2 < nt) WSTAGE(t & 1, (t + 2) * 32);   // buf t&1 free after BAR
        }
    }

    #undef ALOAD
    #undef ADSW
    #undef WSTAGE
    #undef COMPUTE

    __syncthreads();   // release LDS; reuse as C staging tile

    // epilogue: bias + RoPE in regs -> LDS tile -> coalesced 16B stores
    u16* st = smem;                           // 128 x 128 bf16 = 32 KB
    const bool rope_blk = (n0 < 2 * E_);      // q or k column tiles
    #pragma unroll
    for (int mi = 0; mi < 4; ++mi) {
        #pragma unroll
        for (int j = 0; j < 4; ++j) {
            const int row = wm + mi * 16 + fq * 4 + j;
            const int gm = m0 + row;
            int b = 0, s = gm;
            if (gm >= S_) { b = 1; s = gm - S_; }
            const bool rot = rope_blk && (gm < M) && (s > 0);
            const float2* trow = tab + ((size_t)(b * L_ + (s - 1)) << 5);
            #pragma unroll
            for (int ni = 0; ni < 4; ++ni) {
                const int col = wn + ni * 16 + fr;
                const int gn = n0 + col;
                float v = acc[mi][ni][j] + bias[gn];
                const float partner = __shfl_xor(v, 1, 64);  // gn^1 lives in lane^1
                if (rot) {
                    const float2 tt = trow[(gn & 63) >> 1];
                    v = (gn & 1) ? (v * tt.x + partner * tt.y)
                                 : (v * tt.x - partner * tt.y);
                }
                st[row * 128 + col] = f2bf(v);
            }
        }
    }
    __syncthreads();
    #pragma unroll
    for (int i = 0; i < 8; ++i) {
        const int ch = i * 256 + tid;
        const int row = ch >> 4;
        const int coff = (ch & 15) * 8;
        const int gm = m0 + row;
        if (gm < M)
            *(u16x8*)(C + (size_t)gm * N + n0 + coff) =
                *(const u16x8*)(st + row * 128 + coff);
    }
}

// ---------------------------------------------------------------------------
// Out-proj GEMM (fp32 out), 128x128 tile, depth-3 counted-vmcnt pipeline,
// single barrier per step, LDS-staged coalesced C-write.
// ---------------------------------------------------------------------------
__global__ __launch_bounds__(256) void gemm_out_128(
    const u16* __restrict__ A, const u16* __restrict__ W,
    const float* __restrict__ bias, float* __restrict__ C,
    int M, int N, int K)
{
    __shared__ __align__(16) u16 smem[32768];

    const int nwg = gridDim.x * gridDim.y;
    const int orig = blockIdx.y * gridDim.x + blockIdx.x;
    const int qq = nwg >> 3, rr = nwg & 7;
    const int xcd = orig & 7, off = orig >> 3;
    const int wgid = (xcd < rr ? xcd * (qq + 1) : rr * (qq + 1) + (xcd - rr) * qq) + off;
    const int m0 = (wgid / gridDim.x) * 128;
    const int n0 = (wgid % gridDim.x) * 128;

    const int tid  = threadIdx.x;
    const int wid  = tid >> 6;
    const int lane = tid & 63;
    const int wm = (wid >> 1) * 64;
    const int wn = (wid & 1) * 64;

    const int srow = lane >> 2;
    const int scol = ((lane & 3) ^ ((lane >> 3) & 3)) * 8;
    const int fr = lane & 15;
    const int fq = lane >> 4;
    const int sfq = (fq ^ ((fr >> 1) & 3)) * 8;

    const int c0 = wid * 2, c1 = wid * 2 + 1;
    const u16* ga0 = A + (size_t)(m0 + c0 * 16 + srow) * K + scol;
    const u16* ga1 = A + (size_t)(m0 + c1 * 16 + srow) * K + scol;
    const u16* gb0 = W + (size_t)(n0 + c0 * 16 + srow) * K + scol;
    const u16* gb1 = W + (size_t)(n0 + c1 * 16 + srow) * K + scol;
    const int la0 = c0 * 16 * 32, la1 = c1 * 16 * 32;

    f32x4 acc[4][4] = {};

    #define STAGE(bi, k0)                                       \
        do {                                                    \
            u16* as_ = smem + (bi) * 4096;                      \
            u16* bs_ = smem + 16384 + (bi) * 4096;              \
            gload_lds16(ga0 + (k0), as_ + la0);                 \
            gload_lds16(ga1 + (k0), as_ + la1);                 \
            gload_lds16(gb0 + (k0), bs_ + la0);                 \
            gload_lds16(gb1 + (k0), bs_ + la1);                 \
        } while (0)

    #define COMPUTE(bi)                                                          \
        do {                                                                     \
            const u16* as_ = smem + (bi) * 4096;                                 \
            const u16* bs_ = smem + 16384 + (bi) * 4096;                         \
            bf16x8 a[4], b[4];                                                   \
            _Pragma("unroll")                                                    \
            for (int mi = 0; mi < 4; ++mi)                                       \
                a[mi] = *(const bf16x8*)(as_ + (wm + mi * 16 + fr) * 32 + sfq);  \
            _Pragma("unroll")                                                    \
            for (int ni = 0; ni < 4; ++ni)                                       \
                b[ni] = *(const bf16x8*)(bs_ + (wn + ni * 16 + fr) * 32 + sfq);  \
            _Pragma("unroll")                                                    \
            for (int mi = 0; mi < 4; ++mi)                                       \
                _Pragma("unroll")                                                \
                for (int ni = 0; ni < 4; ++ni)                                   \
                    acc[mi][ni] = __builtin_amdgcn_mfma_f32_16x16x32_bf16(       \
                        a[mi], b[ni], acc[mi][ni], 0, 0, 0);                     \
        } while (0)

    const int nt = K / 32;

    STAGE(0, 0);
    STAGE(1, 32);
    STAGE(2, 64);

    int t = 0;
    for (; t <= nt - 4; ++t) {
        WAITV8(); BAR();                    // tile t landed for ALL waves
        COMPUTE(t & 3);
        STAGE((t + 3) & 3, (t + 3) * 32);   // buf (t-1)&3: readers done pre-BAR
    }
    WAITV8(); BAR(); COMPUTE(t & 3); ++t;
    WAITV4(); BAR(); COMPUTE(t & 3); ++t;
    WAITV0(); BAR(); COMPUTE(t & 3);

    #undef STAGE
    #undef COMPUTE

    __syncthreads();

    float* stf = (float*)smem;           // 128 x 128 f32 = 64 KB
    #pragma unroll
    for (int mi = 0; mi < 4; ++mi)
        #pragma unroll
        for (int j = 0; j < 4; ++j) {
            const int r = wm + mi * 16 + fq * 4 + j;
            #pragma unroll
            for (int ni = 0; ni < 4; ++ni) {
                const int c = wn + ni * 16 + fr;
                stf[r * 128 + c] = acc[mi][ni][j] + bias[n0 + c];
            }
        }
    __syncthreads();
    #pragma unroll
    for (int i = 0; i < 16; ++i) {
        const int ch = i * 256 + tid;
        const int row = ch >> 5;
        const int coff = (ch & 31) * 4;
        const int gm = m0 + row;
        if (gm < M)
            *(float4*)(C + (size_t)gm * N + n0 + coff) =
                *(const float4*)(stf + row * 128 + coff);
    }
}

// ---------------------------------------------------------------------------
// CLS attention stage 1 (bf16 qkv): flash over S chunks.
// ---------------------------------------------------------------------------
#define NCHUNK 64
#define CLS_ROWS 129   // ceil(8193/64)

__global__ __launch_bounds__(256) void cls_attn_stage1(
    const u16* __restrict__ qkvb, float* __restrict__ part)
{
    const int blk = blockIdx.x;
    const int bh = blk >> 6, ch = blk & 63;
    const int b = bh >> 3, h = bh & 7;
    const int wid = threadIdx.x >> 6, lane = threadIdx.x & 63;
    const size_t base = (size_t)b * S_ * QKV_COLS;

    const float q = bf2f(qkvb[base + h * D_ + lane]);

    const int lo = ch * CLS_ROWS;
    const int hi = (lo + CLS_ROWS < S_) ? lo + CLS_ROWS : S_;

    float m = -1e30f, lsum = 0.f, acc = 0.f;
    for (int j = lo + wid; j < hi; j += 4) {
        const size_t roff = base + (size_t)j * QKV_COLS;
        float t = q * bf2f(qkvb[roff + E_ + h * D_ + lane]);
        #pragma unroll
        for (int o = 32; o; o >>= 1) t += __shfl_xor(t, o, 64);
        t *= SCALE;
        const float mn = fmaxf(m, t);
        const float corr = __expf(m - mn);
        const float p = __expf(t - mn);
        lsum = lsum * corr + p;
        acc = acc * corr + p * bf2f(qkvb[roff + 2 * E_ + h * D_ + lane]);
        m = mn;
    }

    __shared__ float sm[4], sl[4], sacc[4][64];
    if (lane == 0) { sm[wid] = m; sl[wid] = lsum; }
    sacc[wid][lane] = acc;
    __syncthreads();
    if (wid == 0) {
        const float gm = fmaxf(fmaxf(sm[0], sm[1]), fmaxf(sm[2], sm[3]));
        float gl = 0.f, ga = 0.f;
        #pragma unroll
        for (int w = 0; w < 4; ++w) {
            const float c = __expf(sm[w] - gm);
            gl += sl[w] * c;
            ga += sacc[w][lane] * c;
        }
        float* pp = part + ((size_t)bh * NCHUNK + ch) * 66;
        if (lane == 0) { pp[0] = gm; pp[1] = gl; }
        pp[2 + lane] = ga;
    }
}

__global__ __launch_bounds__(64) void cls_attn_stage2(
    const float* __restrict__ part, u16* __restrict__ attnb)
{
    const int bh = blockIdx.x;
    const int lane = threadIdx.x;
    const int b = bh >> 3, h = bh & 7;
    float gm = -1e30f;
    for (int c = 0; c < NCHUNK; ++c)
        gm = fmaxf(gm, part[((size_t)bh * NCHUNK + c) * 66]);
    float gl = 0.f, ga = 0.f;
    for (int c = 0; c < NCHUNK; ++c) {
        const float* pp = part + ((size_t)bh * NCHUNK + c) * 66;
        const float w = __expf(pp[0] - gm);
        gl += pp[1] * w;
        ga += pp[2 + lane] * w;
    }
    attnb[(size_t)(b * S_) * E_ + h * D_ + lane] = f2bf(ga / gl);
}

// ---------------------------------------------------------------------------
// Patch attention: lane = query. Block = 128 threads (2 waves) = 128 queries.
// K then V staged sequentially in one XOR-swizzled LDS buffer.
// ---------------------------------------------------------------------------
#define PQT 128

__global__ __launch_bounds__(128) void patch_attn(
    const u16* __restrict__ qkvb, u16* __restrict__ attnb)
{
    const int blk = blockIdx.x;
    const int qt = blk & 63;
    const int h = (blk >> 6) & 7;
    const int b = blk >> 9;
    const int l0 = qt * PQT;
    const size_t base = (size_t)b * S_ * QKV_COLS;
    const int hoff = h * D_;

    __shared__ u16 kv[144 * 64];
    __shared__ float kc[64], vc[64];

    const int t = threadIdx.x;

    if (t < 64) kc[t] = bf2f(qkvb[base + E_ + hoff + t]);
    else        vc[t - 64] = bf2f(qkvb[base + 2 * E_ + hoff + (t - 64)]);

    #pragma unroll
    for (int i = 0; i < 9; ++i) {
        const int ci = i * 128 + t;
        const int r = ci >> 3, c = ci & 7;
        const int lg = l0 - 8 + r;
        u16x8 v = {};
        if (lg >= 0 && lg < L_)
            v = *(const u16x8*)(qkvb + base + (size_t)(1 + lg) * QKV_COLS + E_ + hoff + c * 8);
        *(u16x8*)(kv + r * 64 + ((c ^ (r & 7)) * 8)) = v;
    }
    __syncthreads();

    const int l = l0 + t;
    const size_t qrow = base + (size_t)(1 + l) * QKV_COLS + hoff;

    float s[10];
    #pragma unroll
    for (int w = 0; w < 10; ++w) s[w] = 0.f;

    #pragma unroll
    for (int c = 0; c < 8; ++c) {
        const u16x8 qv = *(const u16x8*)(qkvb + qrow + c * 8);
        float qf[8];
        #pragma unroll
        for (int i = 0; i < 8; ++i) qf[i] = bf2f(qv[i]);
        #pragma unroll
        for (int i = 0; i < 8; ++i) s[0] += qf[i] * kc[c * 8 + i];
        #pragma unroll
        for (int w = 0; w < 9; ++w) {
            const int kr = t + 2 * w;
            const u16x8 kk = *(const u16x8*)(kv + kr * 64 + ((c ^ (kr & 7)) * 8));
            #pragma unroll
            for (int i = 0; i < 8; ++i) s[1 + w] += qf[i] * bf2f(kk[i]);
        }
    }

    s[0] *= SCALE;
    #pragma unroll
    for (int w = 0; w < 9; ++w) {
        const int lp = l + 2 * w - 8;
        s[1 + w] = (lp >= 0 && lp < L_) ? s[1 + w] * SCALE : -1e30f;
    }
    float m = s[0];
    #pragma unroll
    for (int w = 1; w < 10; ++w) m = fmaxf(m, s[w]);
    float sum = 0.f;
    #pragma unroll
    for (int w = 0; w < 10; ++w) { s[w] = __expf(s[w] - m); sum += s[w]; }
    const float rsum = 1.0f / sum;

    __syncthreads();
    #pragma unroll
    for (int i = 0; i < 9; ++i) {
        const int ci = i * 128 + t;
        const int r = ci >> 3, c = ci & 7;
        const int lg = l0 - 8 + r;
        u16x8 v = {};
        if (lg >= 0 && lg < L_)
            v = *(const u16x8*)(qkvb + base + (size_t)(1 + lg) * QKV_COLS + 2 * E_ + hoff + c * 8);
        *(u16x8*)(kv + r * 64 + ((c ^ (r & 7)) * 8)) = v;
    }
    __syncthreads();

    const size_t orow = (size_t)(b * S_ + 1 + l) * E_ + hoff;
    #pragma unroll
    for (int c = 0; c < 8; ++c) {
        float acc[8];
        #pragma unroll
        for (int i = 0; i < 8; ++i) acc[i] = s[0] * vc[c * 8 + i];
        #pragma unroll
        for (int w = 0; w < 9; ++w) {
            const int vr = t + 2 * w;
            const u16x8 vv = *(const u16x8*)(kv + vr * 64 + ((c ^ (vr & 7)) * 8));
            #pragma unroll
            for (int i = 0; i < 8; ++i) acc[i] += s[1 + w] * bf2f(vv[i]);
        }
        u16x8 o;
        #pragma unroll
        for (int i = 0; i < 8; ++i) o[i] = f2bf(acc[i] * rsum);
        *(u16x8*)(attnb + orow + c * 8) = o;
    }
}

// ---------------------------------------------------------------------------
// Launch
// ---------------------------------------------------------------------------
extern "C" void kernel_launch(void* const* d_in, const int* in_sizes, int n_in,
                              void* d_out, int out_size, void* d_ws, size_t ws_size,
                              hipStream_t stream)
{
    const float* x      = (const float*)d_in[0];
    const int*   coords = (const int*)  d_in[1];
    const float* w_qkv  = (const float*)d_in[2];
    const float* b_qkv  = (const float*)d_in[3];
    const float* w_out  = (const float*)d_in[4];
    const float* b_out  = (const float*)d_in[5];
    float* out = (float*)d_out;

    // workspace layout
    u16*   qkvb  = (u16*)d_ws;                                // M_ROWS x 1536 bf16
    u16*   attnb = qkvb + (size_t)M_ROWS * QKV_COLS;          // M_PAD x 512 bf16
    u16*   wqb   = attnb + (size_t)M_PAD * E_;                // 1536 x 512
    u16*   wob   = wqb + (size_t)QKV_COLS * E_;               // 512 x 512
    float* part  = (float*)(wob + (size_t)E_ * E_);           // 16*64*66 floats
    float2* tab  = (float2*)(part + (size_t)16 * NCHUNK * 66);// B*L*32 float2 (4 MB)

    // 1. convert weights to bf16 + rope table + zero attnb pad rows
    {
        const long t4q = (long)QKV_COLS * E_ / 4;
        convert_bf16_512<<<(t4q + 255) / 256, 256, 0, stream>>>(w_qkv, wqb, QKV_COLS, t4q);
        const long t4o = (long)E_ * E_ / 4;
        convert_bf16_512<<<(t4o + 255) / 256, 256, 0, stream>>>(w_out, wob, E_, t4o);
        rope_table_kernel<<<(B_ * L_ * 32) / 256, 256, 0, stream>>>(coords, tab);
        hipMemsetAsync(attnb + (size_t)M_ROWS * E_, 0,
                       (size_t)(M_PAD - M_ROWS) * E_ * sizeof(u16), stream);
    }

    // 2. QKV projection (A from fp32 x directly) + fused RoPE, bf16 out
    {
        dim3 grid(QKV_COLS / 128, M_PAD / 128);   // 12 x 129
        gemm_qkv_fused<<<grid, 256, 0, stream>>>(
            x, wqb, b_qkv, qkvb, tab, M_ROWS, QKV_COLS, E_);
    }

    // 3. CLS attention
    cls_attn_stage1<<<B_ * H_ * NCHUNK, 256, 0, stream>>>(qkvb, part);
    cls_attn_stage2<<<B_ * H_, 64, 0, stream>>>(part, attnb);

    // 4. Patch windowed attention
    patch_attn<<<B_ * H_ * (L_ / PQT), PQT, 0, stream>>>(qkvb, attnb);

    // 5. Output projection (fp32 out)
    {
        dim3 grid(E_ / 128, M_PAD / 128);
        gemm_out_128<<<grid, 256, 0, stream>>>(
            attnb, wob, b_out, out, M_ROWS, E_, E_);
    }
}